// Round 4
// baseline (226.724 us; speedup 1.0000x reference)
//
#include <hip/hip_runtime.h>
#include <hip/hip_bf16.h>
#include <cstdint>

// SelfAttention: B=4, S=4096, D=256, DK=256, causal, fp32 I/O, bf16 MFMA internals.
// Round 4: conflict-free full-width LDS swizzles (5-bit XOR for K, d>>2 XOR for V),
// flattened perfectly-balanced work partition (NB blocks x ~8.25 kv-tile units,
// 4-wave blocks, single-buffer 66KB LDS -> 2 independent blocks/CU),
// permlane32_swap for PV fragment exchange, LDS-free proj weights, parallel combine.
//
// ws layout:
//   [0)     Wt: 3 x 256 x 256 bf16 (Wq scaled by log2(e)/16)
//   [512K)  Q:  16384 x 256 bf16 row-major
//   [+8M)   K:  16384 x 256 bf16 row-major
//   [+8M)   Vt: [4][256][4096] bf16 (V transposed)
//   [+8M)   part: [slot][128][256] bf16 partial O; then ml: [slot][128] float2

typedef __bf16 b8v __attribute__((ext_vector_type(8)));
typedef __bf16 b4v __attribute__((ext_vector_type(4)));
typedef float  f4v __attribute__((ext_vector_type(4)));
typedef float  f16v __attribute__((ext_vector_type(16)));
typedef int    i4v __attribute__((ext_vector_type(4)));
typedef int    i2v __attribute__((ext_vector_type(2)));

#define MFMA16(a, b, c) __builtin_amdgcn_mfma_f32_16x16x32_bf16((a), (b), (c), 0, 0, 0)
#define MFMA32(a, b, c) __builtin_amdgcn_mfma_f32_32x32x16_bf16((a), (b), (c), 0, 0, 0)

#define GLOAD_LDS(gsrc, ldst)                                                        \
  __builtin_amdgcn_global_load_lds((const __attribute__((address_space(1))) void*)(gsrc), \
                                   (__attribute__((address_space(3))) void*)(ldst), 16, 0, 0)

#define SCALE_Q 0.09016844005f  // log2(e) / sqrt(256)
#define MASKVAL -3.0e38f
#define M0VAL   -1.0e30f

static constexpr int UT = 4224;  // total kv-tile units: 4 batches * sum(2q+2, q=0..31)
static constexpr size_t WS_WT = 0;
static constexpr size_t WS_Q  = 524288;
static constexpr size_t WS_K  = WS_Q + 8388608;
static constexpr size_t WS_VT = WS_K + 8388608;
static constexpr size_t WS_PART = WS_VT + 8388608;

// ---------------------------------------------------------------- prep: W -> Wt bf16
__global__ void prep_wt(const float* __restrict__ Wq, const float* __restrict__ Wk,
                        const float* __restrict__ Wv, __bf16* __restrict__ wt) {
  int gid = blockIdx.x * blockDim.x + threadIdx.x;
  int w = gid >> 16, rem = gid & 65535;
  int c = rem >> 8, d = rem & 255;
  const float* W = (w == 0) ? Wq : (w == 1) ? Wk : Wv;
  float v = W[d * 256 + c];
  if (w == 0) v *= SCALE_Q;
  wt[gid] = (__bf16)v;  // wt[w][c][d] = W[d][c]
}

// ---------------------------------------------------------------- proj: x @ W -> Q,K,Vt
// 768 blocks: ww = bid>>8 (0=Q,1=K,2=V), rb = bid&255 (64-row block).
// Weights read straight from L1/L2 (128KB, hot) -> no LDS/barriers for Q,K.
__global__ void __launch_bounds__(256, 2) proj_qkv(
    const float* __restrict__ x, const __bf16* __restrict__ wt,
    __bf16* __restrict__ Qw, __bf16* __restrict__ Kw, __bf16* __restrict__ Vt) {
  __shared__ __bf16 v_lds[64][72];
  const int tid = threadIdx.x;
  const int wv = tid >> 6, lane = tid & 63, c = lane & 15, g = lane >> 4;
  const int ww = blockIdx.x >> 8, rb = blockIdx.x & 255;
  const int rowbase = rb * 64;
  const int batch = rb >> 6, sblk = rb & 63;

  b8v xf[8];
  {
    const float* xr = x + (size_t)(rowbase + wv * 16 + c) * 256;
#pragma unroll
    for (int ks = 0; ks < 8; ++ks) {
      const float4 a0 = *reinterpret_cast<const float4*>(xr + 32 * ks + 8 * g);
      const float4 a1 = *reinterpret_cast<const float4*>(xr + 32 * ks + 8 * g + 4);
      b8v f;
      f[0] = (__bf16)a0.x; f[1] = (__bf16)a0.y; f[2] = (__bf16)a0.z; f[3] = (__bf16)a0.w;
      f[4] = (__bf16)a1.x; f[5] = (__bf16)a1.y; f[6] = (__bf16)a1.z; f[7] = (__bf16)a1.w;
      xf[ks] = f;
    }
  }
  const __bf16* wbase = wt + (size_t)ww * 65536;
  for (int ct = 0; ct < 4; ++ct) {
    f4v pacc[4];
#pragma unroll
    for (int i = 0; i < 4; ++i) pacc[i] = (f4v){0.f, 0.f, 0.f, 0.f};
#pragma unroll
    for (int ks = 0; ks < 8; ++ks) {
#pragma unroll
      for (int nf = 0; nf < 4; ++nf) {
        const b8v wf = *reinterpret_cast<const b8v*>(
            wbase + (size_t)(ct * 64 + 16 * nf + c) * 256 + 32 * ks + 8 * g);
        pacc[nf] = MFMA16(xf[ks], wf, pacc[nf]);
      }
    }
    if (ww < 2) {
      __bf16* o = (ww == 0) ? Qw : Kw;
      const int row0 = rowbase + wv * 16 + 4 * g;
#pragma unroll
      for (int nf = 0; nf < 4; ++nf) {
        const int col = ct * 64 + 16 * nf + c;
#pragma unroll
        for (int r = 0; r < 4; ++r)
          o[(size_t)(row0 + r) * 256 + col] = (__bf16)pacc[nf][r];
      }
    } else {
      __syncthreads();  // previous ct readback done
      const int sp = 16 * wv + 4 * g;
#pragma unroll
      for (int nf = 0; nf < 4; ++nf) {
        b4v pk;
        pk[0] = (__bf16)pacc[nf][0]; pk[1] = (__bf16)pacc[nf][1];
        pk[2] = (__bf16)pacc[nf][2]; pk[3] = (__bf16)pacc[nf][3];
        *reinterpret_cast<b4v*>(&v_lds[16 * nf + c][sp]) = pk;
      }
      __syncthreads();
      {
        const int dd = tid >> 2, ch = tid & 3;
        const b8v* sp8 = reinterpret_cast<const b8v*>(&v_lds[dd][ch * 16]);
        __bf16* dst =
            Vt + ((size_t)(batch * 256 + ct * 64 + dd)) * 4096 + sblk * 64 + ch * 16;
        reinterpret_cast<b8v*>(dst)[0] = sp8[0];
        reinterpret_cast<b8v*>(dst)[1] = sp8[1];
      }
    }
  }
}

// ---------------------------------------------------------------- flash attention
// Work unit = one (batch, 128-row q-tile, 64-row kv-tile). Segment (bb,q) has
// len=2q+2 units. Block b processes units [b*UT/NB, (b+1)*UT/NB) as runs; a run
// covering a whole segment writes fp32 out; else bf16 partial + (m,l).
// LDS (66KB, single buffer, 2 blocks/CU):
//   K: chunk(r,c) at r*512 + ((c^(r&31))<<4        (r<64, c<32)  -> conflict-free
//   V: chunk(d,c) at d*128 + ((c^((d>>2)&7))<<4    (d<256, c<8)  -> conflict-free
__global__ void __launch_bounds__(256, 2) attn_fwd(
    const __bf16* __restrict__ Qw, const __bf16* __restrict__ Kw,
    const __bf16* __restrict__ Vt, float* __restrict__ out,
    __bf16* __restrict__ part, float* __restrict__ ml, int NB) {
  extern __shared__ char smem[];
  char* Klds = smem;           // 32KB
  char* Vlds = smem + 32768;   // 32KB
  float* bc = reinterpret_cast<float*>(smem + 65536);  // [4][32]

  const int tid = threadIdx.x;
  const int wv = tid >> 6, lane = tid & 63;
  const int q5 = lane & 31, hi = lane >> 5;

  int u = (int)(((long long)blockIdx.x * UT) / NB);
  const int u1 = (int)(((long long)(blockIdx.x + 1) * UT) / NB);

  while (u < u1) {
    const int bb = u / 1056;
    const int r0 = u - bb * 1056;
    int q = 0;
    while ((q + 1) * (q + 2) <= r0) ++q;
    const int g0 = bb * 1056 + q * (q + 1);
    const int len = 2 * q + 2;
    const int ge = g0 + len;
    const int re = (u1 < ge) ? u1 : ge;
    const int ta = u - g0, tb = re - g0;
    const bool direct = (ta == 0) && (tb == len);

    const __bf16* Kg = Kw + (size_t)bb * 4096 * 256;
    const __bf16* Vg = Vt + (size_t)bb * 256 * 4096;

    b8v qf[16];
    {
      const __bf16* qr =
          Qw + ((size_t)(bb * 4096 + q * 128 + wv * 32 + q5)) * 256 + 8 * hi;
#pragma unroll
      for (int ks = 0; ks < 16; ++ks)
        qf[ks] = *reinterpret_cast<const b8v*>(qr + ks * 16);
    }

    f16v acc[8];
#pragma unroll
    for (int i = 0; i < 8; ++i)
#pragma unroll
      for (int j = 0; j < 16; ++j) acc[i][j] = 0.f;
    float m = M0VAL, lsum = 0.f;
    const int qg = q * 128 + wv * 32 + q5;
    const char* kb0 = Klds + q5 * 512;

    for (int t = ta; t < tb; ++t) {
      __syncthreads();  // all waves done reading previous tile
      // stage K (2048 chunks) + V (2048 chunks), pre-permuted global source
#pragma unroll
      for (int i = 0; i < 8; ++i) {
        const int n = i * 256 + tid;
        const int rr = n >> 5, cp = n & 31;
        const __bf16* src =
            Kg + (size_t)(t * 64 + rr) * 256 + ((cp ^ (rr & 31)) << 3);
        GLOAD_LDS(src, Klds + ((i * 256 + wv * 64) << 4));
      }
#pragma unroll
      for (int i = 0; i < 8; ++i) {
        const int n = i * 256 + tid;
        const int d = n >> 3, cp = n & 7;
        const __bf16* src =
            Vg + (size_t)d * 4096 + t * 64 + ((cp ^ ((d >> 2) & 7)) << 3);
        GLOAD_LDS(src, Vlds + ((i * 256 + wv * 64) << 4));
      }
      __syncthreads();  // implies vmcnt(0) drain -> LDS ready

      // S^T = K * Q^T : s0 kv rows 0-31, s1 rows 32-63; col = q5
      f16v s0, s1;
#pragma unroll
      for (int j = 0; j < 16; ++j) { s0[j] = 0.f; s1[j] = 0.f; }
      __builtin_amdgcn_s_setprio(1);
#pragma unroll
      for (int ks = 0; ks < 16; ++ks) {
        const int co = (((ks << 1) | hi) ^ q5) << 4;
        const b8v k0 = *reinterpret_cast<const b8v*>(kb0 + co);
        const b8v k1 = *reinterpret_cast<const b8v*>(kb0 + 16384 + co);
        s0 = MFMA32(k0, qf[ks], s0);
        s1 = MFMA32(k1, qf[ks], s1);
      }
      __builtin_amdgcn_s_setprio(0);

      if (t * 64 + 63 > q * 128 + wv * 32) {  // causal mask
#pragma unroll
        for (int reg = 0; reg < 16; ++reg) {
          const int R = (reg & 3) + 8 * (reg >> 2) + 4 * hi;
          if (t * 64 + R > qg) s0[reg] = MASKVAL;
          if (t * 64 + 32 + R > qg) s1[reg] = MASKVAL;
        }
      }
      // lane-local max
      float p0 = s0[0], p1 = s0[1], p2 = s0[2], p3 = s0[3];
#pragma unroll
      for (int j = 4; j < 16; j += 4) {
        p0 = fmaxf(p0, s0[j]); p1 = fmaxf(p1, s0[j + 1]);
        p2 = fmaxf(p2, s0[j + 2]); p3 = fmaxf(p3, s0[j + 3]);
      }
#pragma unroll
      for (int j = 0; j < 16; j += 4) {
        p0 = fmaxf(p0, s1[j]); p1 = fmaxf(p1, s1[j + 1]);
        p2 = fmaxf(p2, s1[j + 2]); p3 = fmaxf(p3, s1[j + 3]);
      }
      const float pm = fmaxf(fmaxf(p0, p1), fmaxf(p2, p3));

      if (!__all(pm - m <= 8.0f)) {  // deferred rescale
        const float pm2 = fmaxf(pm, __shfl_xor(pm, 32));
        const float mnew = fmaxf(m, pm2);
        const float fac = exp2f(m - mnew);
        bc[wv * 32 + q5] = fac;
        lsum *= fac;
        m = mnew;
#pragma unroll
        for (int reg = 0; reg < 16; ++reg) {
          const float fr = bc[wv * 32 + ((reg & 3) + 8 * (reg >> 2) + 4 * hi)];
#pragma unroll
          for (int db = 0; db < 8; ++db) acc[db][reg] *= fr;
        }
      }
#pragma unroll
      for (int j = 0; j < 16; ++j) {
        s0[j] = exp2f(s0[j] - m);
        s1[j] = exp2f(s1[j] - m);
      }
      {
        float u0 = 0.f, u1s = 0.f, u2 = 0.f, u3 = 0.f;
#pragma unroll
        for (int j = 0; j < 16; j += 4) {
          u0 += s0[j]; u1s += s0[j + 1]; u2 += s0[j + 2]; u3 += s0[j + 3];
          u0 += s1[j]; u1s += s1[j + 1]; u2 += s1[j + 2]; u3 += s1[j + 3];
        }
        lsum += (u0 + u1s) + (u2 + u3);
      }
      // pack P -> bf16 quads
      unsigned a0[8], a1[8];
#pragma unroll
      for (int mb = 0; mb < 4; ++mb) {
        b4v pk;
        pk[0] = (__bf16)s0[4 * mb]; pk[1] = (__bf16)s0[4 * mb + 1];
        pk[2] = (__bf16)s0[4 * mb + 2]; pk[3] = (__bf16)s0[4 * mb + 3];
        const uint2 uu = *reinterpret_cast<uint2*>(&pk);
        a0[mb] = uu.x; a1[mb] = uu.y;
      }
#pragma unroll
      for (int mb = 0; mb < 4; ++mb) {
        b4v pk;
        pk[0] = (__bf16)s1[4 * mb]; pk[1] = (__bf16)s1[4 * mb + 1];
        pk[2] = (__bf16)s1[4 * mb + 2]; pk[3] = (__bf16)s1[4 * mb + 3];
        const uint2 uu = *reinterpret_cast<uint2*>(&pk);
        a0[4 + mb] = uu.x; a1[4 + mb] = uu.y;
      }
      // O += P * V (half-exchange via permlane32_swap: d.hi <-> s.lo)
#pragma unroll
      for (int ks = 0; ks < 4; ++ks) {
        i4v wi;
#if __has_builtin(__builtin_amdgcn_permlane32_swap)
        const i2v e0 = __builtin_amdgcn_permlane32_swap((int)a0[2 * ks],
                                                        (int)a0[2 * ks + 1], false, false);
        const i2v e1 = __builtin_amdgcn_permlane32_swap((int)a1[2 * ks],
                                                        (int)a1[2 * ks + 1], false, false);
        wi[0] = e0[0]; wi[1] = e1[0]; wi[2] = e0[1]; wi[3] = e1[1];
#else
        const unsigned x0 = (unsigned)__shfl_xor((int)a0[2 * ks], 32);
        const unsigned x1 = (unsigned)__shfl_xor((int)a1[2 * ks], 32);
        const unsigned y0 = (unsigned)__shfl_xor((int)a0[2 * ks + 1], 32);
        const unsigned y1 = (unsigned)__shfl_xor((int)a1[2 * ks + 1], 32);
        wi[0] = hi ? (int)y0 : (int)a0[2 * ks];
        wi[1] = hi ? (int)y1 : (int)a1[2 * ks];
        wi[2] = hi ? (int)a0[2 * ks + 1] : (int)x0;
        wi[3] = hi ? (int)a1[2 * ks + 1] : (int)x1;
#endif
        const b8v pa = *reinterpret_cast<b8v*>(&wi);
        const int cov = (((ks << 1) | hi) ^ (q5 >> 2)) << 4;
        __builtin_amdgcn_s_setprio(1);
#pragma unroll
        for (int db = 0; db < 8; ++db) {
          const b8v vf =
              *reinterpret_cast<const b8v*>(Vlds + (q5 + 32 * db) * 128 + cov);
          acc[db] = MFMA32(pa, vf, acc[db]);
        }
        __builtin_amdgcn_s_setprio(0);
      }
    }  // tiles

    lsum += __shfl_xor(lsum, 32);
    if (direct) {
      const float inv = 1.f / lsum;
      bc[wv * 32 + q5] = inv;
#pragma unroll
      for (int reg = 0; reg < 16; ++reg) {
        const int R = (reg & 3) + 8 * (reg >> 2) + 4 * hi;
        const float ivr = bc[wv * 32 + R];
        float* orow =
            out + ((size_t)(bb * 4096 + q * 128 + wv * 32 + R)) * 256 + q5;
#pragma unroll
        for (int db = 0; db < 8; ++db) orow[db * 32] = acc[db][reg] * ivr;
      }
    } else {
      // compact slot = (#partial runs in segments before this) + run idx
      const int sidx = bb * 32 + q;
      int base = 0;
      for (int s = 0; s < sidx; ++s) {
        const int sq = s & 31, sbb = s >> 5;
        const int h0 = sbb * 1056 + sq * (sq + 1);
        const int h1 = h0 + 2 * sq + 2;
        const int k = (h1 * NB + UT - 1) / UT - ((h0 + 1) * NB + UT - 1) / UT;
        if (k > 0) base += k + 1;
      }
      const int idx = ((u + 1) * NB + UT - 1) / UT - ((g0 + 1) * NB + UT - 1) / UT;
      const int slot = base + idx;
      __bf16* pbase = part + (size_t)slot * 32768;
#pragma unroll
      for (int reg = 0; reg < 16; ++reg) {
        const int R = (reg & 3) + 8 * (reg >> 2) + 4 * hi;
        __bf16* prow = pbase + (size_t)(wv * 32 + R) * 256 + q5;
#pragma unroll
        for (int db = 0; db < 8; ++db) prow[db * 32] = (__bf16)acc[db][reg];
      }
      if (hi == 0) {
        float2* ml2 = reinterpret_cast<float2*>(ml);
        ml2[(size_t)slot * 128 + wv * 32 + q5] = make_float2(m, lsum);
      }
    }
    u = re;
  }
}

// ---------------------------------------------------------------- combine partials
// grid 128*4: sidx = bid>>2 (segment), rq = bid&3 (32-row quarter).
__global__ void __launch_bounds__(256) combine_k(
    const __bf16* __restrict__ part, const float* __restrict__ ml,
    float* __restrict__ out, int NB) {
  const int sidx = blockIdx.x >> 2, rq = blockIdx.x & 3;
  const int bb = sidx >> 5, q = sidx & 31;
  const int g0 = bb * 1056 + q * (q + 1);
  const int g1 = g0 + 2 * q + 2;
  const int nbi = (g1 * NB + UT - 1) / UT - ((g0 + 1) * NB + UT - 1) / UT;
  if (nbi <= 0) return;
  const int nch = nbi + 1;
  int base = 0;
  for (int s = 0; s < sidx; ++s) {
    const int sq = s & 31, sbb = s >> 5;
    const int h0 = sbb * 1056 + sq * (sq + 1);
    const int h1 = h0 + 2 * sq + 2;
    const int k = (h1 * NB + UT - 1) / UT - ((h0 + 1) * NB + UT - 1) / UT;
    if (k > 0) base += k + 1;
  }
  const int row = rq * 32 + (threadIdx.x >> 3);
  const int c0 = (threadIdx.x & 7) * 32;
  const float2* ml2 = reinterpret_cast<const float2*>(ml);

  float mx = MASKVAL;
  for (int cc = 0; cc < nch; ++cc)
    mx = fmaxf(mx, ml2[(size_t)(base + cc) * 128 + row].x);
  float den = 0.f;
  for (int cc = 0; cc < nch; ++cc) {
    const float2 p = ml2[(size_t)(base + cc) * 128 + row];
    den += exp2f(p.x - mx) * p.y;
  }
  const float inv = 1.f / den;
  f4v o4[8];
#pragma unroll
  for (int i = 0; i < 8; ++i) o4[i] = (f4v){0.f, 0.f, 0.f, 0.f};
  for (int cc = 0; cc < nch; ++cc) {
    const float w = exp2f(ml2[(size_t)(base + cc) * 128 + row].x - mx) * inv;
    const b8v* src = reinterpret_cast<const b8v*>(
        part + ((size_t)(base + cc) * 128 + row) * 256 + c0);
#pragma unroll
    for (int k = 0; k < 4; ++k) {
      const b8v v = src[k];
#pragma unroll
      for (int j = 0; j < 4; ++j) {
        o4[2 * k][j] += w * (float)v[j];
        o4[2 * k + 1][j] += w * (float)v[4 + j];
      }
    }
  }
  float* dst = out + ((size_t)(bb * 4096 + q * 128 + row)) * 256 + c0;
#pragma unroll
  for (int k = 0; k < 8; ++k) reinterpret_cast<f4v*>(dst)[k] = o4[k];
}

// ---------------------------------------------------------------- launch
extern "C" void kernel_launch(void* const* d_in, const int* in_sizes, int n_in,
                              void* d_out, int out_size, void* d_ws, size_t ws_size,
                              hipStream_t stream) {
  const float* x  = reinterpret_cast<const float*>(d_in[0]);
  const float* Wq = reinterpret_cast<const float*>(d_in[1]);
  const float* Wk = reinterpret_cast<const float*>(d_in[2]);
  const float* Wv = reinterpret_cast<const float*>(d_in[3]);
  char* ws = reinterpret_cast<char*>(d_ws);
  __bf16* wt = reinterpret_cast<__bf16*>(ws + WS_WT);
  __bf16* Qw = reinterpret_cast<__bf16*>(ws + WS_Q);
  __bf16* Kw = reinterpret_cast<__bf16*>(ws + WS_K);
  __bf16* Vt = reinterpret_cast<__bf16*>(ws + WS_VT);
  float* out = reinterpret_cast<float*>(d_out);

  // pick NB (block count) so exact partial-slot storage fits in ws
  const int cand[5] = {512, 384, 256, 128, 64};
  int NB = 64, slots = 0;
  for (int ci = 0; ci < 5; ++ci) {
    const int nb = cand[ci];
    int sl = 0;
    for (int s = 0; s < 128; ++s) {
      const int sq = s & 31, sbb = s >> 5;
      const int h0 = sbb * 1056 + sq * (sq + 1);
      const int h1 = h0 + 2 * sq + 2;
      const int k = (h1 * nb + UT - 1) / UT - ((h0 + 1) * nb + UT - 1) / UT;
      if (k > 0) sl += k + 1;
    }
    const size_t need = WS_PART + (size_t)sl * 65536 + (size_t)sl * 1024;
    if (ws_size >= need) { NB = nb; slots = sl; break; }
  }
  __bf16* part = reinterpret_cast<__bf16*>(ws + WS_PART);
  float* mlp = reinterpret_cast<float*>(ws + WS_PART + (size_t)slots * 65536);

  prep_wt<<<768, 256, 0, stream>>>(Wq, Wk, Wv, wt);
  proj_qkv<<<768, 256, 0, stream>>>(x, wt, Qw, Kw, Vt);

  constexpr int kSmem = 66048;  // 32KB K + 32KB V + bc
  (void)hipFuncSetAttribute(reinterpret_cast<const void*>(attn_fwd),
                            hipFuncAttributeMaxDynamicSharedMemorySize, kSmem);
  attn_fwd<<<NB, 256, kSmem, stream>>>(Qw, Kw, Vt, out, part, mlp, NB);
  combine_k<<<512, 256, 0, stream>>>(part, mlp, out, NB);
}

// Round 6
// 162.592 us; speedup vs baseline: 1.3944x; 1.3944x over previous
//
#include <hip/hip_runtime.h>
#include <hip/hip_bf16.h>
#include <cstdint>

// SelfAttention: B=4, S=4096, D=256, DK=256, causal, fp32 I/O, bf16 MFMA internals.
// Round 6 (= Round 5 with compile fix): XCD batch pinning, KVBLK=32 double-buffered
// prefetch (stage(next) before compute, 1 barrier/tile, 64KB LDS -> 2 blocks/CU),
// conflict-free K/V swizzles, LDS-staged proj weights.
// Fix: no pointer arrays initialized from extern __shared__ (addrspacecast static
// initializer error on gfx950) — buffers selected by runtime byte offsets.
//
// ws layout:
//   [0)     Wt: 3 x 256 x 256 bf16 (Wq scaled by log2(e)/16)
//   [512K)  Q:  16384 x 256 bf16 row-major
//   [+8M)   K:  16384 x 256 bf16 row-major
//   [+8M)   Vt: [4][256][4096] bf16 (V transposed)
//   [+8M)   part: [slot][128][256] bf16 partial O; then ml: [slot][128] float2

typedef __bf16 b8v __attribute__((ext_vector_type(8)));
typedef __bf16 b4v __attribute__((ext_vector_type(4)));
typedef float  f4v __attribute__((ext_vector_type(4)));
typedef float  f16v __attribute__((ext_vector_type(16)));
typedef int    i4v __attribute__((ext_vector_type(4)));
typedef int    i2v __attribute__((ext_vector_type(2)));

#define MFMA16(a, b, c) __builtin_amdgcn_mfma_f32_16x16x32_bf16((a), (b), (c), 0, 0, 0)
#define MFMA32(a, b, c) __builtin_amdgcn_mfma_f32_32x32x16_bf16((a), (b), (c), 0, 0, 0)

#define GLOAD_LDS(gsrc, ldst)                                                        \
  __builtin_amdgcn_global_load_lds((const __attribute__((address_space(1))) void*)(gsrc), \
                                   (__attribute__((address_space(3))) void*)(ldst), 16, 0, 0)

#define SCALE_Q 0.09016844005f  // log2(e) / sqrt(256)
#define MASKVAL -3.0e38f
#define M0VAL   -1.0e30f

static constexpr int UT = 4224;  // 4 batches * sum(2q+2, q=0..31) 64-row kv units
static constexpr size_t WS_WT = 0;
static constexpr size_t WS_Q  = 524288;
static constexpr size_t WS_K  = WS_Q + 8388608;
static constexpr size_t WS_VT = WS_K + 8388608;
static constexpr size_t WS_PART = WS_VT + 8388608;

// ---------------------------------------------------------------- prep: W -> Wt bf16
__global__ void prep_wt(const float* __restrict__ Wq, const float* __restrict__ Wk,
                        const float* __restrict__ Wv, __bf16* __restrict__ wt) {
  int gid = blockIdx.x * blockDim.x + threadIdx.x;
  int w = gid >> 16, rem = gid & 65535;
  int c = rem >> 8, d = rem & 255;
  const float* W = (w == 0) ? Wq : (w == 1) ? Wk : Wv;
  float v = W[d * 256 + c];
  if (w == 0) v *= SCALE_Q;
  wt[gid] = (__bf16)v;  // wt[w][c][d] = W[d][c]
}

// ---------------------------------------------------------------- proj: x @ W -> Q,K,Vt
// 768 blocks: ww = bid>>8 (0=Q,1=K,2=V), rb = bid&255. Weights staged in LDS.
__global__ void __launch_bounds__(256, 2) proj_qkv(
    const float* __restrict__ x, const __bf16* __restrict__ wt,
    __bf16* __restrict__ Qw, __bf16* __restrict__ Kw, __bf16* __restrict__ Vt) {
  __shared__ __bf16 w_lds[64][264];
  __shared__ __bf16 v_lds[64][72];
  const int tid = threadIdx.x;
  const int wv = tid >> 6, lane = tid & 63, c = lane & 15, g = lane >> 4;
  const int ww = blockIdx.x >> 8, rb = blockIdx.x & 255;
  const int rowbase = rb * 64;
  const int batch = rb >> 6, sblk = rb & 63;

  b8v xf[8];
  {
    const float* xr = x + (size_t)(rowbase + wv * 16 + c) * 256;
#pragma unroll
    for (int ks = 0; ks < 8; ++ks) {
      const float4 a0 = *reinterpret_cast<const float4*>(xr + 32 * ks + 8 * g);
      const float4 a1 = *reinterpret_cast<const float4*>(xr + 32 * ks + 8 * g + 4);
      b8v f;
      f[0] = (__bf16)a0.x; f[1] = (__bf16)a0.y; f[2] = (__bf16)a0.z; f[3] = (__bf16)a0.w;
      f[4] = (__bf16)a1.x; f[5] = (__bf16)a1.y; f[6] = (__bf16)a1.z; f[7] = (__bf16)a1.w;
      xf[ks] = f;
    }
  }
  const int srow = tid >> 2, sch = tid & 3;
  for (int ct = 0; ct < 4; ++ct) {
    __syncthreads();
    {
      const i4v* src = reinterpret_cast<const i4v*>(
          wt + ((size_t)(ww * 256 + ct * 64 + srow)) * 256 + sch * 64);
      i4v* dst = reinterpret_cast<i4v*>(&w_lds[srow][sch * 64]);
#pragma unroll
      for (int j = 0; j < 8; ++j) dst[j] = src[j];
    }
    __syncthreads();
    f4v pacc[4];
#pragma unroll
    for (int i = 0; i < 4; ++i) pacc[i] = (f4v){0.f, 0.f, 0.f, 0.f};
#pragma unroll
    for (int ks = 0; ks < 8; ++ks) {
#pragma unroll
      for (int nf = 0; nf < 4; ++nf) {
        b8v wf = *reinterpret_cast<const b8v*>(&w_lds[16 * nf + c][32 * ks + 8 * g]);
        pacc[nf] = MFMA16(xf[ks], wf, pacc[nf]);
      }
    }
    if (ww < 2) {
      __bf16* o = (ww == 0) ? Qw : Kw;
      const int row0 = rowbase + wv * 16 + 4 * g;
#pragma unroll
      for (int nf = 0; nf < 4; ++nf) {
        const int col = ct * 64 + 16 * nf + c;
#pragma unroll
        for (int r = 0; r < 4; ++r)
          o[(size_t)(row0 + r) * 256 + col] = (__bf16)pacc[nf][r];
      }
    } else {
      const int sp = 16 * wv + 4 * g;
#pragma unroll
      for (int nf = 0; nf < 4; ++nf) {
        b4v pk;
        pk[0] = (__bf16)pacc[nf][0]; pk[1] = (__bf16)pacc[nf][1];
        pk[2] = (__bf16)pacc[nf][2]; pk[3] = (__bf16)pacc[nf][3];
        *reinterpret_cast<b4v*>(&v_lds[16 * nf + c][sp]) = pk;
      }
      __syncthreads();
      {
        const int dd = tid >> 2, ch = tid & 3;
        const b8v* sp8 = reinterpret_cast<const b8v*>(&v_lds[dd][ch * 16]);
        __bf16* dst =
            Vt + ((size_t)(batch * 256 + ct * 64 + dd)) * 4096 + sblk * 64 + ch * 16;
        reinterpret_cast<b8v*>(dst)[0] = sp8[0];
        reinterpret_cast<b8v*>(dst)[1] = sp8[1];
      }
    }
  }
}

// ---------------------------------------------------------------- flash attention
// Work unit = (batch, 128-row q-tile, 64-row kv unit); processed as two 32-row
// kv tiles. Logical blocks partition the UT units contiguously; physical->logical
// remap pins each batch to one XCD pair (K/V = 4MB = one XCD L2).
// LDS layout (buffer s at byte offset s*32768):
//   K: chunk c of row r at r*512 + ((c^r)<<4)              (r<32, c<32)
//   V: 16384 + d*64 + ((c^((d>>3)&3))<<4)                  (d<256, c<4)
// Loop: stage(next tile, other buffer) -> compute(current) -> one __syncthreads.
__global__ void __launch_bounds__(256, 2) attn_fwd(
    const __bf16* __restrict__ Qw, const __bf16* __restrict__ Kw,
    const __bf16* __restrict__ Vt, float* __restrict__ out,
    __bf16* __restrict__ part, float* __restrict__ ml, int NB) {
  extern __shared__ char smem[];
  float* bc = reinterpret_cast<float*>(smem + 65536);  // [4][32]

  const int tid = threadIdx.x;
  const int wv = tid >> 6, lane = tid & 63;
  const int q5 = lane & 31, hi = lane >> 5;

  // physical -> logical remap: XCD pair (p&7)>>1 owns batch (p&7)>>1
  const int p = blockIdx.x, xcd = p & 7;
  const int lb = (xcd >> 1) * (NB >> 2) + (xcd & 1) * (NB >> 3) + (p >> 3);

  int u = (int)(((long long)lb * UT) / NB);
  const int u1 = (int)(((long long)(lb + 1) * UT) / NB);

  while (u < u1) {
    const int bb = u / 1056;
    const int r0 = u - bb * 1056;
    int q = 0;
    while ((q + 1) * (q + 2) <= r0) ++q;
    const int g0 = bb * 1056 + q * (q + 1);
    const int len = 2 * q + 2;
    const int ge = g0 + len;
    const int re = (u1 < ge) ? u1 : ge;
    const int ta = u - g0, tb = re - g0;
    const bool direct = (ta == 0) && (tb == len);

    const __bf16* Kg = Kw + (size_t)bb * 4096 * 256;
    const __bf16* Vg = Vt + (size_t)bb * 256 * 4096;

    // stage one 32-row kv tile tt into buffer s (pre-swizzled global source)
    auto stage = [&](int s, int tt) {
      char* Kd = smem + s * 32768;
      char* Vd = Kd + 16384;
#pragma unroll
      for (int i = 0; i < 4; ++i) {
        const int n = i * 256 + tid;
        const int r = n >> 5, cp = n & 31;
        const __bf16* src = Kg + (size_t)(tt * 32 + r) * 256 + ((cp ^ r) << 3);
        GLOAD_LDS(src, Kd + ((i * 256 + wv * 64) << 4));
      }
#pragma unroll
      for (int i = 0; i < 4; ++i) {
        const int n = i * 256 + tid;
        const int d = n >> 2, cp = n & 3;
        const __bf16* src =
            Vg + (size_t)d * 4096 + tt * 32 + ((cp ^ ((d >> 3) & 3)) << 3);
        GLOAD_LDS(src, Vd + ((i * 256 + wv * 64) << 4));
      }
    };

    b8v qf[16];
    {
      const __bf16* qr =
          Qw + ((size_t)(bb * 4096 + q * 128 + wv * 32 + q5)) * 256 + 8 * hi;
#pragma unroll
      for (int ks = 0; ks < 16; ++ks)
        qf[ks] = *reinterpret_cast<const b8v*>(qr + ks * 16);
    }

    f16v acc[8];
#pragma unroll
    for (int i = 0; i < 8; ++i)
#pragma unroll
      for (int j = 0; j < 16; ++j) acc[i][j] = 0.f;
    float m = M0VAL, lsum = 0.f;
    const int qg = q * 128 + wv * 32 + q5;
    const int ttEnd = 2 * tb;

    stage(0, 2 * ta);
    __syncthreads();

    for (int tt = 2 * ta; tt < ttEnd; ++tt) {
      const int cur = tt & 1;
      if (tt + 1 < ttEnd) stage(cur ^ 1, tt + 1);  // prefetch into other buffer

      // S^T = K * Q^T : 32 kv rows; lane holds S^T[R(reg,hi)][q5]
      f16v s;
#pragma unroll
      for (int j = 0; j < 16; ++j) s[j] = 0.f;
      const char* kb0 = smem + cur * 32768 + q5 * 512;
      __builtin_amdgcn_s_setprio(1);
#pragma unroll
      for (int ks = 0; ks < 16; ++ks) {
        const int co = (((ks << 1) | hi) ^ q5) << 4;
        const b8v k0 = *reinterpret_cast<const b8v*>(kb0 + co);
        s = MFMA32(k0, qf[ks], s);
      }
      __builtin_amdgcn_s_setprio(0);

      if (tt * 32 + 31 > q * 128 + wv * 32) {  // causal mask
#pragma unroll
        for (int reg = 0; reg < 16; ++reg) {
          const int R = (reg & 3) + 8 * (reg >> 2) + 4 * hi;
          if (tt * 32 + R > qg) s[reg] = MASKVAL;
        }
      }
      // lane-local max over 16
      float p0 = s[0], p1 = s[1], p2 = s[2], p3 = s[3];
#pragma unroll
      for (int j = 4; j < 16; j += 4) {
        p0 = fmaxf(p0, s[j]); p1 = fmaxf(p1, s[j + 1]);
        p2 = fmaxf(p2, s[j + 2]); p3 = fmaxf(p3, s[j + 3]);
      }
      const float pm = fmaxf(fmaxf(p0, p1), fmaxf(p2, p3));

      if (!__all(pm - m <= 8.0f)) {  // deferred rescale (rare)
        const float pm2 = fmaxf(pm, __shfl_xor(pm, 32));
        const float mnew = fmaxf(m, pm2);
        const float fac = exp2f(m - mnew);
        bc[wv * 32 + q5] = fac;
        lsum *= fac;
        m = mnew;
#pragma unroll
        for (int reg = 0; reg < 16; ++reg) {
          const float fr = bc[wv * 32 + ((reg & 3) + 8 * (reg >> 2) + 4 * hi)];
#pragma unroll
          for (int db = 0; db < 8; ++db) acc[db][reg] *= fr;
        }
      }
#pragma unroll
      for (int j = 0; j < 16; ++j) s[j] = exp2f(s[j] - m);
      {
        float u0 = 0.f, u1s = 0.f, u2 = 0.f, u3 = 0.f;
#pragma unroll
        for (int j = 0; j < 16; j += 4) {
          u0 += s[j]; u1s += s[j + 1]; u2 += s[j + 2]; u3 += s[j + 3];
        }
        lsum += (u0 + u1s) + (u2 + u3);
      }
      // pack P -> bf16 quads
      unsigned a0[4], a1[4];
#pragma unroll
      for (int mb = 0; mb < 4; ++mb) {
        b4v pk;
        pk[0] = (__bf16)s[4 * mb]; pk[1] = (__bf16)s[4 * mb + 1];
        pk[2] = (__bf16)s[4 * mb + 2]; pk[3] = (__bf16)s[4 * mb + 3];
        const uint2 uu = *reinterpret_cast<uint2*>(&pk);
        a0[mb] = uu.x; a1[mb] = uu.y;
      }
      // O += P * V  (half-exchange via permlane32_swap)
      const char* vbase = smem + cur * 32768 + 16384 + q5 * 64;
#pragma unroll
      for (int ks = 0; ks < 2; ++ks) {
        i4v wi;
#if __has_builtin(__builtin_amdgcn_permlane32_swap)
        const i2v e0 = __builtin_amdgcn_permlane32_swap((int)a0[2 * ks],
                                                        (int)a0[2 * ks + 1], false, false);
        const i2v e1 = __builtin_amdgcn_permlane32_swap((int)a1[2 * ks],
                                                        (int)a1[2 * ks + 1], false, false);
        wi[0] = e0[0]; wi[1] = e1[0]; wi[2] = e0[1]; wi[3] = e1[1];
#else
        const unsigned x0 = (unsigned)__shfl_xor((int)a0[2 * ks], 32);
        const unsigned x1 = (unsigned)__shfl_xor((int)a1[2 * ks], 32);
        const unsigned y0 = (unsigned)__shfl_xor((int)a0[2 * ks + 1], 32);
        const unsigned y1 = (unsigned)__shfl_xor((int)a1[2 * ks + 1], 32);
        wi[0] = hi ? (int)y0 : (int)a0[2 * ks];
        wi[1] = hi ? (int)y1 : (int)a1[2 * ks];
        wi[2] = hi ? (int)a0[2 * ks + 1] : (int)x0;
        wi[3] = hi ? (int)a1[2 * ks + 1] : (int)x1;
#endif
        const b8v pa = *reinterpret_cast<b8v*>(&wi);
        const int cov = ((((ks << 1) | hi)) ^ ((q5 >> 3) & 3)) << 4;
        __builtin_amdgcn_s_setprio(1);
#pragma unroll
        for (int db = 0; db < 8; ++db) {
          const b8v vf =
              *reinterpret_cast<const b8v*>(vbase + db * 2048 + cov);
          acc[db] = MFMA32(pa, vf, acc[db]);
        }
        __builtin_amdgcn_s_setprio(0);
      }
      __syncthreads();  // drains this iter's prefetch; all readers done
    }  // tiles

    lsum += __shfl_xor(lsum, 32);
    if (direct) {
      const float inv = 1.f / lsum;
      bc[wv * 32 + q5] = inv;
#pragma unroll
      for (int reg = 0; reg < 16; ++reg) {
        const int R = (reg & 3) + 8 * (reg >> 2) + 4 * hi;
        const float ivr = bc[wv * 32 + R];
        float* orow =
            out + ((size_t)(bb * 4096 + q * 128 + wv * 32 + R)) * 256 + q5;
#pragma unroll
        for (int db = 0; db < 8; ++db) orow[db * 32] = acc[db][reg] * ivr;
      }
    } else {
      const int sidx = bb * 32 + q;
      int base = 0;
      for (int sdx = 0; sdx < sidx; ++sdx) {
        const int sq = sdx & 31, sbb = sdx >> 5;
        const int h0 = sbb * 1056 + sq * (sq + 1);
        const int h1 = h0 + 2 * sq + 2;
        const int k = (h1 * NB + UT - 1) / UT - ((h0 + 1) * NB + UT - 1) / UT;
        if (k > 0) base += k + 1;
      }
      const int idx = ((u + 1) * NB + UT - 1) / UT - ((g0 + 1) * NB + UT - 1) / UT;
      const int slot = base + idx;
      __bf16* pbase = part + (size_t)slot * 32768;
#pragma unroll
      for (int reg = 0; reg < 16; ++reg) {
        const int R = (reg & 3) + 8 * (reg >> 2) + 4 * hi;
        __bf16* prow = pbase + (size_t)(wv * 32 + R) * 256 + q5;
#pragma unroll
        for (int db = 0; db < 8; ++db) prow[db * 32] = (__bf16)acc[db][reg];
      }
      if (hi == 0) {
        float2* ml2 = reinterpret_cast<float2*>(ml);
        ml2[(size_t)slot * 128 + wv * 32 + q5] = make_float2(m, lsum);
      }
    }
    u = re;
  }
}

// ---------------------------------------------------------------- combine partials
__global__ void __launch_bounds__(256) combine_k(
    const __bf16* __restrict__ part, const float* __restrict__ ml,
    float* __restrict__ out, int NB) {
  const int sidx = blockIdx.x >> 2, rq = blockIdx.x & 3;
  const int bb = sidx >> 5, q = sidx & 31;
  const int g0 = bb * 1056 + q * (q + 1);
  const int g1 = g0 + 2 * q + 2;
  const int nbi = (g1 * NB + UT - 1) / UT - ((g0 + 1) * NB + UT - 1) / UT;
  if (nbi <= 0) return;
  const int nch = nbi + 1;
  int base = 0;
  for (int s = 0; s < sidx; ++s) {
    const int sq = s & 31, sbb = s >> 5;
    const int h0 = sbb * 1056 + sq * (sq + 1);
    const int h1 = h0 + 2 * sq + 2;
    const int k = (h1 * NB + UT - 1) / UT - ((h0 + 1) * NB + UT - 1) / UT;
    if (k > 0) base += k + 1;
  }
  const int row = rq * 32 + (threadIdx.x >> 3);
  const int c0 = (threadIdx.x & 7) * 32;
  const float2* ml2 = reinterpret_cast<const float2*>(ml);

  float mx = MASKVAL;
  for (int cc = 0; cc < nch; ++cc)
    mx = fmaxf(mx, ml2[(size_t)(base + cc) * 128 + row].x);
  float den = 0.f;
  for (int cc = 0; cc < nch; ++cc) {
    const float2 pr = ml2[(size_t)(base + cc) * 128 + row];
    den += exp2f(pr.x - mx) * pr.y;
  }
  const float inv = 1.f / den;
  f4v o4[8];
#pragma unroll
  for (int i = 0; i < 8; ++i) o4[i] = (f4v){0.f, 0.f, 0.f, 0.f};
  for (int cc = 0; cc < nch; ++cc) {
    const float w = exp2f(ml2[(size_t)(base + cc) * 128 + row].x - mx) * inv;
    const b8v* src = reinterpret_cast<const b8v*>(
        part + ((size_t)(base + cc) * 128 + row) * 256 + c0);
#pragma unroll
    for (int k = 0; k < 4; ++k) {
      const b8v v = src[k];
#pragma unroll
      for (int j = 0; j < 4; ++j) {
        o4[2 * k][j] += w * (float)v[j];
        o4[2 * k + 1][j] += w * (float)v[4 + j];
      }
    }
  }
  float* dst = out + ((size_t)(bb * 4096 + q * 128 + row)) * 256 + c0;
#pragma unroll
  for (int k = 0; k < 8; ++k) reinterpret_cast<f4v*>(dst)[k] = o4[k];
}

// ---------------------------------------------------------------- launch
extern "C" void kernel_launch(void* const* d_in, const int* in_sizes, int n_in,
                              void* d_out, int out_size, void* d_ws, size_t ws_size,
                              hipStream_t stream) {
  const float* x  = reinterpret_cast<const float*>(d_in[0]);
  const float* Wq = reinterpret_cast<const float*>(d_in[1]);
  const float* Wk = reinterpret_cast<const float*>(d_in[2]);
  const float* Wv = reinterpret_cast<const float*>(d_in[3]);
  char* ws = reinterpret_cast<char*>(d_ws);
  __bf16* wt = reinterpret_cast<__bf16*>(ws + WS_WT);
  __bf16* Qw = reinterpret_cast<__bf16*>(ws + WS_Q);
  __bf16* Kw = reinterpret_cast<__bf16*>(ws + WS_K);
  __bf16* Vt = reinterpret_cast<__bf16*>(ws + WS_VT);
  float* out = reinterpret_cast<float*>(d_out);

  // pick NB (multiple of 8 for the XCD remap) so partial-slot storage fits ws
  const int cand[5] = {512, 384, 256, 128, 64};
  int NB = 64, slots = 0;
  for (int ci = 0; ci < 5; ++ci) {
    const int nb = cand[ci];
    int sl = 0;
    for (int s = 0; s < 128; ++s) {
      const int sq = s & 31, sbb = s >> 5;
      const int h0 = sbb * 1056 + sq * (sq + 1);
      const int h1 = h0 + 2 * sq + 2;
      const int k = (h1 * nb + UT - 1) / UT - ((h0 + 1) * nb + UT - 1) / UT;
      if (k > 0) sl += k + 1;
    }
    const size_t need = WS_PART + (size_t)sl * 65536 + (size_t)sl * 1024;
    if (ws_size >= need) { NB = nb; slots = sl; break; }
  }
  __bf16* part = reinterpret_cast<__bf16*>(ws + WS_PART);
  float* mlp = reinterpret_cast<float*>(ws + WS_PART + (size_t)slots * 65536);

  prep_wt<<<768, 256, 0, stream>>>(Wq, Wk, Wv, wt);
  proj_qkv<<<768, 256, 0, stream>>>(x, wt, Qw, Kw, Vt);

  constexpr int kSmem = 66048;  // 2 x (16KB K + 16KB V) + bc
  (void)hipFuncSetAttribute(reinterpret_cast<const void*>(attn_fwd),
                            hipFuncAttributeMaxDynamicSharedMemorySize, kSmem);
  attn_fwd<<<NB, 256, kSmem, stream>>>(Qw, Kw, Vt, out, part, mlp, NB);
  combine_k<<<512, 256, 0, stream>>>(part, mlp, out, NB);
}